// Round 6
// baseline (1383.724 us; speedup 1.0000x reference)
//
#include <hip/hip_runtime.h>
#include <hip/hip_bf16.h>

#define NNODES 100000
#define NEDGES 1600000
#define INF 512
#define OUTF 128
#define NB 1563         // buckets of 64 nodes: bucket = dst >> 6
#define BCAP 1536       // mean 1024, sigma ~32 -> 16 sigma headroom
#define SEG 4096        // edges per block in bucket_kernel
#define BK 32           // gemm k-step (floats)
#define NKSTEP (INF / BK)

typedef __attribute__((ext_vector_type(8))) __bf16 bf16x8;
typedef __attribute__((ext_vector_type(4))) float f32x4;
typedef __attribute__((ext_vector_type(2))) float f32x2;

typedef const __attribute__((address_space(1))) unsigned int* gas_ptr;
typedef __attribute__((address_space(3))) unsigned int* las_ptr;

__device__ __forceinline__ void gload_lds16(const void* g, void* l) {
  __builtin_amdgcn_global_load_lds((gas_ptr)g, (las_ptr)l, 16, 0, 0);
}

// ---------------- weight f32 [512][128] -> bf16 fragment-ordered ------------
// short index (((kb*8 + c)*16 + l15)*4 + lg)*8 + j = W[kb*32+lg*8+j][c*16+l15]
__global__ void wt_kernel(const float* __restrict__ w, unsigned short* __restrict__ wta) {
  int i = blockIdx.x * blockDim.x + threadIdx.x;   // 0..8191
  if (i >= 8192) return;
  int lg  = i & 3;
  int l15 = (i >> 2) & 15;
  int c   = (i >> 6) & 7;
  int kb  = i >> 9;
  int n = c * 16 + l15;
  int kbase = kb * 32 + lg * 8;
  unsigned short tmp[8];
#pragma unroll
  for (int j = 0; j < 8; ++j) {
    __bf16 b = (__bf16)(w[(size_t)(kbase + j) * OUTF + n]);
    tmp[j] = __builtin_bit_cast(unsigned short, b);
  }
  ((int4*)wta)[i] = *(int4*)tmp;
}

// ---------------- pass A: bucket edges by dst>>6, histogram src out-degree ---
__global__ __launch_bounds__(256) void bucket_kernel(
    const int* __restrict__ src, const int* __restrict__ dst,
    const float* __restrict__ ew, int* __restrict__ out_cnt,
    int* __restrict__ bucket_cnt, int2* __restrict__ bucket) {
  __shared__ int hist[NB];
  __shared__ int base[NB];
  int t = threadIdx.x;
  for (int i = t; i < NB; i += 256) hist[i] = 0;
  __syncthreads();
  int e0 = blockIdx.x * SEG;
  int e1 = min(e0 + SEG, NEDGES);
  for (int e = e0 + t; e < e1; e += 256) {
    atomicAdd(&out_cnt[src[e]], 1);
    atomicAdd(&hist[dst[e] >> 6], 1);
  }
  __syncthreads();
  for (int i = t; i < NB; i += 256) {
    int c = hist[i];
    base[i] = c ? atomicAdd(&bucket_cnt[i], c) : 0;
    hist[i] = 0;                       // reuse as cursor
  }
  __syncthreads();
  for (int e = e0 + t; e < e1; e += 256) {
    int d = dst[e];
    int b = d >> 6;
    int r = atomicAdd(&hist[b], 1);
    int2 en;
    en.x = ((d & 63) << 17) | src[e];  // src < 2^17
    en.y = __float_as_int(ew[e]);
    bucket[(size_t)b * BCAP + base[b] + r] = en;
  }
}

// ---------------- h = (feat * rsqrt(out_deg)) @ W, LDS-staged MFMA ----------
// block tile 128 rows x 128 cols, BK=32; 4 waves, each 32 rows.
// A: LDS dbuf [128][32] f32, chunk-XOR-swizzled, staged via global_load_lds
//    with pre-swizzled per-lane global source (linear LDS dest).
// B: loaded per K-step straight from L2-resident fragment-ordered wta.
// h output layout is PAIR-SPLIT: u32 slot k of a row = (feat k, feat 64+k).
__global__ __launch_bounds__(256, 3) void gemm_kernel(
    const float* __restrict__ feat, const unsigned short* __restrict__ wta,
    const int* __restrict__ out_cnt, unsigned short* __restrict__ h) {
  __shared__ float As[2][128 * BK];            // 16 KB each

  const int t = threadIdx.x;
  const int lane = t & 63;
  const int wave = t >> 6;
  const int l15 = lane & 15;
  const int lg  = lane >> 4;
  const int rowbase = blockIdx.x * 128;

  const int srow_off = lane >> 3;              // 0..7
  const int schunk = (lane & 7) ^ srow_off;    // pre-swizzled source chunk

  int r0 = rowbase + wave * 32 + l15;
  int r1 = r0 + 16;
  float s0 = rsqrtf(fmaxf((float)out_cnt[min(r0, NNODES - 1)], 1.0f));
  float s1 = rsqrtf(fmaxf((float)out_cnt[min(r1, NNODES - 1)], 1.0f));

  f32x4 acc[2][8];
#pragma unroll
  for (int f = 0; f < 2; ++f)
#pragma unroll
    for (int c = 0; c < 8; ++c) acc[f][c] = (f32x4){0.f, 0.f, 0.f, 0.f};

#define STAGE_A(buf, kb)                                                       \
  {                                                                            \
    _Pragma("unroll")                                                          \
    for (int q = 0; q < 4; ++q) {                                              \
      int gr = min(rowbase + wave * 32 + q * 8 + srow_off, NNODES - 1);        \
      const float* gsrc = feat + (size_t)gr * INF + (kb) * BK + schunk * 4;    \
      gload_lds16(gsrc, &As[buf][(wave * 4 + q) * 256]);                       \
    }                                                                          \
  }

  int buf = 0;
  STAGE_A(0, 0);
  __syncthreads();

  for (int kb = 0; kb < NKSTEP; ++kb) {
    if (kb + 1 < NKSTEP) STAGE_A(buf ^ 1, kb + 1);

    // B fragments straight from L2 (coalesced 1 KB per instruction)
    bf16x8 bfr[8];
#pragma unroll
    for (int c = 0; c < 8; ++c)
      bfr[c] = *(const bf16x8*)(wta + (size_t)kb * 4096 + c * 512 + l15 * 32 + lg * 8);

    // A fragments from LDS (XOR-swizzled chunks), scale + cvt to bf16
    bf16x8 afr[2];
#pragma unroll
    for (int rf = 0; rf < 2; ++rf) {
      int r = wave * 32 + rf * 16 + l15;
      int c0 = (lg * 2) ^ (l15 & 7);
      int c1 = (lg * 2 + 1) ^ (l15 & 7);
      f32x4 u = *(const f32x4*)&As[buf][r * 32 + c0 * 4];
      f32x4 v = *(const f32x4*)&As[buf][r * 32 + c1 * 4];
      float s = rf ? s1 : s0;
      bf16x8 a;
#pragma unroll
      for (int j = 0; j < 4; ++j) {
        a[j]     = (__bf16)(u[j] * s);
        a[j + 4] = (__bf16)(v[j] * s);
      }
      afr[rf] = a;
    }

#pragma unroll
    for (int c = 0; c < 8; ++c) {
      acc[0][c] = __builtin_amdgcn_mfma_f32_16x16x32_bf16(afr[0], bfr[c], acc[0][c], 0, 0, 0);
      acc[1][c] = __builtin_amdgcn_mfma_f32_16x16x32_bf16(afr[1], bfr[c], acc[1][c], 0, 0, 0);
    }

    __syncthreads();
    buf ^= 1;
  }
#undef STAGE_A

  // pair-split epilogue: feat f=c*16+l15 -> short idx row*128 + 2*((c&3)*16+l15) + (c>>2)
#pragma unroll
  for (int f = 0; f < 2; ++f) {
    int rb = rowbase + wave * 32 + f * 16 + lg * 4;
#pragma unroll
    for (int r = 0; r < 4; ++r) {
      int row = rb + r;
      if (row < NNODES) {
#pragma unroll
        for (int c = 0; c < 8; ++c) {
          __bf16 bv = (__bf16)acc[f][c][r];
          h[(size_t)row * 128 + 2 * ((c & 3) * 16 + l15) + (c >> 2)] =
              __builtin_bit_cast(unsigned short, bv);
        }
      }
    }
  }
}

// ---------------- accumulate: one block per 64-node bucket ------------------
// LDS f32 accumulator [64 nodes][128 feats]; lane j handles feats j, j+64
// (pair-split h row: u32 slot j = (feat j, feat j+64)) -> stride-1 native
// ds_add_f32 via unsafeAtomicAdd (plain atomicAdd on LDS f32 = CAS loop!).
__global__ __launch_bounds__(256) void accum_kernel(
    const int* __restrict__ bucket_cnt, const int2* __restrict__ bucket,
    const unsigned int* __restrict__ hp, const float* __restrict__ bias,
    float* __restrict__ out) {
  __shared__ float acc[64 * 128];
  __shared__ int cnt[64];
  const int b = blockIdx.x;
  const int t = threadIdx.x;
  const int lane = t & 63;
  const int wave = t >> 6;

  for (int i = t; i < 64 * 128; i += 256) acc[i] = 0.f;
  if (t < 64) cnt[t] = 0;
  __syncthreads();

  const int nb = bucket_cnt[b];
  const int2* bk = bucket + (size_t)b * BCAP;

  for (int base = wave * 64; base < nb; base += 256) {
    int j = base + lane;
    int2 pr = make_int2(0, 0);
    if (j < nb) {
      pr = bk[j];
      atomicAdd(&cnt[pr.x >> 17], 1);
    }
    int cn = min(nb - base, 64);
    int ti = 0;
    for (; ti + 4 <= cn; ti += 4) {
      int e0 = __shfl(pr.x, ti);
      int e1 = __shfl(pr.x, ti + 1);
      int e2 = __shfl(pr.x, ti + 2);
      int e3 = __shfl(pr.x, ti + 3);
      float w0 = __int_as_float(__shfl(pr.y, ti));
      float w1 = __int_as_float(__shfl(pr.y, ti + 1));
      float w2 = __int_as_float(__shfl(pr.y, ti + 2));
      float w3 = __int_as_float(__shfl(pr.y, ti + 3));
      unsigned int u0 = hp[(size_t)(e0 & 0x1FFFF) * 64 + lane];
      unsigned int u1 = hp[(size_t)(e1 & 0x1FFFF) * 64 + lane];
      unsigned int u2 = hp[(size_t)(e2 & 0x1FFFF) * 64 + lane];
      unsigned int u3 = hp[(size_t)(e3 & 0x1FFFF) * 64 + lane];
      int d0 = (e0 >> 17) << 7, d1 = (e1 >> 17) << 7;
      int d2 = (e2 >> 17) << 7, d3 = (e3 >> 17) << 7;
      unsafeAtomicAdd(&acc[d0 + lane],      __uint_as_float(u0 << 16) * w0);
      unsafeAtomicAdd(&acc[d0 + 64 + lane], __uint_as_float(u0 & 0xFFFF0000u) * w0);
      unsafeAtomicAdd(&acc[d1 + lane],      __uint_as_float(u1 << 16) * w1);
      unsafeAtomicAdd(&acc[d1 + 64 + lane], __uint_as_float(u1 & 0xFFFF0000u) * w1);
      unsafeAtomicAdd(&acc[d2 + lane],      __uint_as_float(u2 << 16) * w2);
      unsafeAtomicAdd(&acc[d2 + 64 + lane], __uint_as_float(u2 & 0xFFFF0000u) * w2);
      unsafeAtomicAdd(&acc[d3 + lane],      __uint_as_float(u3 << 16) * w3);
      unsafeAtomicAdd(&acc[d3 + 64 + lane], __uint_as_float(u3 & 0xFFFF0000u) * w3);
    }
    for (; ti < cn; ++ti) {
      int e = __shfl(pr.x, ti);
      float w = __int_as_float(__shfl(pr.y, ti));
      unsigned int u = hp[(size_t)(e & 0x1FFFF) * 64 + lane];
      int d = (e >> 17) << 7;
      unsafeAtomicAdd(&acc[d + lane],      __uint_as_float(u << 16) * w);
      unsafeAtomicAdd(&acc[d + 64 + lane], __uint_as_float(u & 0xFFFF0000u) * w);
    }
  }
  __syncthreads();

  // write-out: out[node] = acc * rsqrt(max(indeg,1)) + bias
  for (int i = t; i < 64 * 64; i += 256) {
    int nl = i >> 6;            // node local
    int p  = i & 63;            // f32x2 index within row
    int node = b * 64 + nl;
    if (node < NNODES) {
      float sc = rsqrtf(fmaxf((float)cnt[nl], 1.0f));
      f32x2 bv = *((const f32x2*)bias + p);
      f32x2 r;
      r.x = acc[nl * 128 + 2 * p]     * sc + bv.x;
      r.y = acc[nl * 128 + 2 * p + 1] * sc + bv.y;
      *((f32x2*)(out + (size_t)node * OUTF) + p) = r;
    }
  }
}

extern "C" void kernel_launch(void* const* d_in, const int* in_sizes, int n_in,
                              void* d_out, int out_size, void* d_ws, size_t ws_size,
                              hipStream_t stream) {
  const float* feat   = (const float*)d_in[0];
  const float* weight = (const float*)d_in[1];
  const float* bias   = (const float*)d_in[2];
  const float* ew     = (const float*)d_in[3];
  const int*   src    = (const int*)d_in[4];
  const int*   dst    = (const int*)d_in[5];
  float* out = (float*)d_out;
  char* ws = (char*)d_ws;

  int* out_cnt        = (int*)ws;                          // 400 KB
  int* bucket_cnt     = (int*)(ws + 0x80000);              // 6.3 KB
  unsigned short* wta = (unsigned short*)(ws + 0x90000);   // 128 KB
  int2* bucket        = (int2*)(ws + 0xB0000);             // 19.2 MB
  unsigned short* h   = (unsigned short*)(ws + 0x1400000); // 25.6 MB

  hipMemsetAsync(out_cnt, 0, NNODES * sizeof(int), stream);
  hipMemsetAsync(bucket_cnt, 0, NB * sizeof(int), stream);

  wt_kernel<<<32, 256, 0, stream>>>(weight, wta);
  bucket_kernel<<<(NEDGES + SEG - 1) / SEG, 256, 0, stream>>>(src, dst, ew, out_cnt,
                                                              bucket_cnt, bucket);
  gemm_kernel<<<(NNODES + 127) / 128, 256, 0, stream>>>(feat, wta, out_cnt, h);
  accum_kernel<<<NB, 256, 0, stream>>>(bucket_cnt, bucket, (const unsigned int*)h,
                                       bias, out);
}

// Round 7
// 270.114 us; speedup vs baseline: 5.1227x; 5.1227x over previous
//
#include <hip/hip_runtime.h>
#include <hip/hip_bf16.h>

#define NNODES 100000
#define NEDGES 1600000
#define INF 512
#define OUTF 128
#define NB 391          // buckets of 256 nodes: bucket = dst >> 8
#define BCAP 5120       // mean 4096, sigma ~64 -> 16 sigma headroom
#define SEG 4096        // edges per block in bucket_kernel
#define BK 32           // gemm k-step (floats)
#define NKSTEP (INF / BK)

typedef __attribute__((ext_vector_type(8))) __bf16 bf16x8;
typedef __attribute__((ext_vector_type(4))) float f32x4;
typedef __attribute__((ext_vector_type(2))) float f32x2;

typedef const __attribute__((address_space(1))) unsigned int* gas_ptr;
typedef __attribute__((address_space(3))) unsigned int* las_ptr;

__device__ __forceinline__ void gload_lds16(const void* g, void* l) {
  __builtin_amdgcn_global_load_lds((gas_ptr)g, (las_ptr)l, 16, 0, 0);
}

// ---------------- weight f32 [512][128] -> bf16 fragment-ordered ------------
// short index (((kb*8 + c)*16 + l15)*4 + lg)*8 + j = W[kb*32+lg*8+j][c*16+l15]
__global__ void wt_kernel(const float* __restrict__ w, unsigned short* __restrict__ wta) {
  int i = blockIdx.x * blockDim.x + threadIdx.x;   // 0..8191
  if (i >= 8192) return;
  int lg  = i & 3;
  int l15 = (i >> 2) & 15;
  int c   = (i >> 6) & 7;
  int kb  = i >> 9;
  int n = c * 16 + l15;
  int kbase = kb * 32 + lg * 8;
  unsigned short tmp[8];
#pragma unroll
  for (int j = 0; j < 8; ++j) {
    __bf16 b = (__bf16)(w[(size_t)(kbase + j) * OUTF + n]);
    tmp[j] = __builtin_bit_cast(unsigned short, b);
  }
  ((int4*)wta)[i] = *(int4*)tmp;
}

// ---------------- pass A: bucket edges by dst>>8, histogram src out-degree ---
__global__ __launch_bounds__(256) void bucket_kernel(
    const int* __restrict__ src, const int* __restrict__ dst,
    const float* __restrict__ ew, int* __restrict__ out_cnt,
    int* __restrict__ bucket_cnt, int2* __restrict__ bucket) {
  __shared__ int hist[NB];
  __shared__ int base[NB];
  int t = threadIdx.x;
  for (int i = t; i < NB; i += 256) hist[i] = 0;
  __syncthreads();
  int e0 = blockIdx.x * SEG;
  int e1 = min(e0 + SEG, NEDGES);
  for (int e = e0 + t; e < e1; e += 256) {
    atomicAdd(&out_cnt[src[e]], 1);
    atomicAdd(&hist[dst[e] >> 8], 1);
  }
  __syncthreads();
  for (int i = t; i < NB; i += 256) {
    int c = hist[i];
    base[i] = c ? atomicAdd(&bucket_cnt[i], c) : 0;
    hist[i] = 0;                       // reuse as cursor
  }
  __syncthreads();
  for (int e = e0 + t; e < e1; e += 256) {
    int d = dst[e];
    int b = d >> 8;
    int r = atomicAdd(&hist[b], 1);
    int2 en;
    en.x = ((d & 255) << 17) | src[e];  // src < 2^17
    en.y = __float_as_int(ew[e]);
    bucket[(size_t)b * BCAP + base[b] + r] = en;
  }
}

// ---------------- exclusive scan of bucket counts (1 block) -----------------
__global__ __launch_bounds__(512) void bscan_kernel(const int* __restrict__ bucket_cnt,
                                                    int* __restrict__ bucket_base,
                                                    int* __restrict__ rowptr) {
  __shared__ int s[512];
  int t = threadIdx.x;
  int v = (t < NB) ? bucket_cnt[t] : 0;
  s[t] = v;
  __syncthreads();
  for (int off = 1; off < 512; off <<= 1) {
    int x = (t >= off) ? s[t - off] : 0;
    __syncthreads();
    s[t] += x;
    __syncthreads();
  }
  if (t < NB) bucket_base[t] = s[t] - v;
  if (t == 0) rowptr[NNODES] = NEDGES;
}

// ---------------- pass B: bucket -> CSR (rowptr + epair) --------------------
__global__ __launch_bounds__(256) void csr_kernel(
    const int* __restrict__ bucket_cnt, const int* __restrict__ bucket_base,
    const int2* __restrict__ bucket, int* __restrict__ rowptr,
    int2* __restrict__ epair) {
  __shared__ int hist[256];
  __shared__ int cur[256];
  int b = blockIdx.x;
  int t = threadIdx.x;
  int nb = bucket_cnt[b];
  int bbase = bucket_base[b];
  const int2* bk = bucket + (size_t)b * BCAP;
  hist[t] = 0;
  __syncthreads();
  for (int i = t; i < nb; i += 256) atomicAdd(&hist[bk[i].x >> 17], 1);
  __syncthreads();
  int v = hist[t];
  for (int off = 1; off < 256; off <<= 1) {
    int x = (t >= off) ? hist[t - off] : 0;
    __syncthreads();
    hist[t] += x;
    __syncthreads();
  }
  int excl = hist[t] - v;
  int node = b * 256 + t;
  if (node < NNODES) rowptr[node] = bbase + excl;
  cur[t] = excl;
  __syncthreads();
  for (int i = t; i < nb; i += 256) {
    int2 en = bk[i];
    int nl = en.x >> 17;
    int r = atomicAdd(&cur[nl], 1);
    epair[bbase + r] = make_int2(en.x & 0x1FFFF, en.y);
  }
}

// ---------------- h = (feat * rsqrt(out_deg)) @ W, LDS-staged MFMA ----------
// block tile 128 rows x 128 cols, BK=32; 4 waves, each 32 rows.
// A: LDS dbuf [128][32] f32, chunk-XOR-swizzled, staged via global_load_lds
//    with pre-swizzled per-lane global source (linear LDS dest).
// B: loaded per K-step straight from L2-resident fragment-ordered wta.
// h output: PLAIN bf16 row layout h[row][f].
__global__ __launch_bounds__(256, 3) void gemm_kernel(
    const float* __restrict__ feat, const unsigned short* __restrict__ wta,
    const int* __restrict__ out_cnt, unsigned short* __restrict__ h) {
  __shared__ float As[2][128 * BK];            // 16 KB each

  const int t = threadIdx.x;
  const int lane = t & 63;
  const int wave = t >> 6;
  const int l15 = lane & 15;
  const int lg  = lane >> 4;
  const int rowbase = blockIdx.x * 128;

  const int srow_off = lane >> 3;              // 0..7
  const int schunk = (lane & 7) ^ srow_off;    // pre-swizzled source chunk

  int r0 = rowbase + wave * 32 + l15;
  int r1 = r0 + 16;
  float s0 = rsqrtf(fmaxf((float)out_cnt[min(r0, NNODES - 1)], 1.0f));
  float s1 = rsqrtf(fmaxf((float)out_cnt[min(r1, NNODES - 1)], 1.0f));

  f32x4 acc[2][8];
#pragma unroll
  for (int f = 0; f < 2; ++f)
#pragma unroll
    for (int c = 0; c < 8; ++c) acc[f][c] = (f32x4){0.f, 0.f, 0.f, 0.f};

#define STAGE_A(buf, kb)                                                       \
  {                                                                            \
    _Pragma("unroll")                                                          \
    for (int q = 0; q < 4; ++q) {                                              \
      int gr = min(rowbase + wave * 32 + q * 8 + srow_off, NNODES - 1);        \
      const float* gsrc = feat + (size_t)gr * INF + (kb) * BK + schunk * 4;    \
      gload_lds16(gsrc, &As[buf][(wave * 4 + q) * 256]);                       \
    }                                                                          \
  }

  int buf = 0;
  STAGE_A(0, 0);
  __syncthreads();

  for (int kb = 0; kb < NKSTEP; ++kb) {
    if (kb + 1 < NKSTEP) STAGE_A(buf ^ 1, kb + 1);

    // B fragments straight from L2 (coalesced 1 KB per instruction)
    bf16x8 bfr[8];
#pragma unroll
    for (int c = 0; c < 8; ++c)
      bfr[c] = *(const bf16x8*)(wta + (size_t)kb * 4096 + c * 512 + l15 * 32 + lg * 8);

    // A fragments from LDS (XOR-swizzled chunks), scale + cvt to bf16
    bf16x8 afr[2];
#pragma unroll
    for (int rf = 0; rf < 2; ++rf) {
      int r = wave * 32 + rf * 16 + l15;
      int c0 = (lg * 2) ^ (l15 & 7);
      int c1 = (lg * 2 + 1) ^ (l15 & 7);
      f32x4 u = *(const f32x4*)&As[buf][r * 32 + c0 * 4];
      f32x4 v = *(const f32x4*)&As[buf][r * 32 + c1 * 4];
      float s = rf ? s1 : s0;
      bf16x8 a;
#pragma unroll
      for (int j = 0; j < 4; ++j) {
        a[j]     = (__bf16)(u[j] * s);
        a[j + 4] = (__bf16)(v[j] * s);
      }
      afr[rf] = a;
    }

#pragma unroll
    for (int c = 0; c < 8; ++c) {
      acc[0][c] = __builtin_amdgcn_mfma_f32_16x16x32_bf16(afr[0], bfr[c], acc[0][c], 0, 0, 0);
      acc[1][c] = __builtin_amdgcn_mfma_f32_16x16x32_bf16(afr[1], bfr[c], acc[1][c], 0, 0, 0);
    }

    __syncthreads();
    buf ^= 1;
  }
#undef STAGE_A

#pragma unroll
  for (int f = 0; f < 2; ++f) {
    int rb = rowbase + wave * 32 + f * 16 + lg * 4;
#pragma unroll
    for (int r = 0; r < 4; ++r) {
      int row = rb + r;
      if (row < NNODES) {
#pragma unroll
        for (int c = 0; c < 8; ++c) {
          __bf16 bv = (__bf16)acc[f][c][r];
          h[(size_t)row * OUTF + c * 16 + l15] = __builtin_bit_cast(unsigned short, bv);
        }
      }
    }
  }
}

// ---------------- gather: group-split register accumulation -----------------
// one wave per dst node (grid-stride); 4 lane-groups of 16 handle interleaved
// edges of the SAME node; lane li covers feats li*8..li*8+7 (uint4 of bf16).
// No atomics, no shfl-broadcast in the hot loop; 4-deep unroll -> 16 h-row
// loads in flight per wave. Cross-group reduce: shfl_xor(16), shfl_xor(32).
__device__ __forceinline__ float blo(unsigned int u) { return __uint_as_float(u << 16); }
__device__ __forceinline__ float bhi(unsigned int u) { return __uint_as_float(u & 0xFFFF0000u); }

__global__ __launch_bounds__(256) void gather_kernel(
    const int* __restrict__ rowptr, const int2* __restrict__ epair,
    const unsigned short* __restrict__ h, const float* __restrict__ bias,
    float* __restrict__ out) {
  const int lane = threadIdx.x & 63;
  const int grp  = lane >> 4;          // 0..3: edge interleave slot
  const int li   = lane & 15;          // feature slice: feats li*8..li*8+7
  const int wid  = (blockIdx.x * blockDim.x + threadIdx.x) >> 6;
  const int nw   = (gridDim.x * blockDim.x) >> 6;

  for (int node = wid; node < NNODES; node += nw) {
    const int beg = rowptr[node];
    const int end = rowptr[node + 1];

    float a0 = 0.f, a1 = 0.f, a2 = 0.f, a3 = 0.f;
    float a4 = 0.f, a5 = 0.f, a6 = 0.f, a7 = 0.f;

    int e = beg + grp;
#define GSTEP(pr)                                                              \
      {                                                                        \
        const unsigned int* hp =                                               \
            (const unsigned int*)(h + (size_t)(pr).x * OUTF) + li * 4;         \
        uint4 u = *(const uint4*)hp;                                           \
        float w = __int_as_float((pr).y);                                      \
        a0 += blo(u.x) * w; a1 += bhi(u.x) * w;                                \
        a2 += blo(u.y) * w; a3 += bhi(u.y) * w;                                \
        a4 += blo(u.z) * w; a5 += bhi(u.z) * w;                                \
        a6 += blo(u.w) * w; a7 += bhi(u.w) * w;                                \
      }
    for (; e + 12 < end; e += 16) {
      int2 p0 = epair[e];
      int2 p1 = epair[e + 4];
      int2 p2 = epair[e + 8];
      int2 p3 = epair[e + 12];
      GSTEP(p0); GSTEP(p1); GSTEP(p2); GSTEP(p3);
    }
    for (; e < end; e += 4) {
      int2 p = epair[e];
      GSTEP(p);
    }
#undef GSTEP

    // reduce across the 4 lane-groups (lanes differing in bits 4,5)
    a0 += __shfl_xor(a0, 16); a1 += __shfl_xor(a1, 16);
    a2 += __shfl_xor(a2, 16); a3 += __shfl_xor(a3, 16);
    a4 += __shfl_xor(a4, 16); a5 += __shfl_xor(a5, 16);
    a6 += __shfl_xor(a6, 16); a7 += __shfl_xor(a7, 16);
    a0 += __shfl_xor(a0, 32); a1 += __shfl_xor(a1, 32);
    a2 += __shfl_xor(a2, 32); a3 += __shfl_xor(a3, 32);
    a4 += __shfl_xor(a4, 32); a5 += __shfl_xor(a5, 32);
    a6 += __shfl_xor(a6, 32); a7 += __shfl_xor(a7, 32);

    float sc = rsqrtf(fmaxf((float)(end - beg), 1.0f));
    if (grp == 0) {
      f32x4 bv = ((const f32x4*)bias)[li * 2];
      f32x4 r;
      r.x = a0 * sc + bv.x; r.y = a1 * sc + bv.y;
      r.z = a2 * sc + bv.z; r.w = a3 * sc + bv.w;
      ((f32x4*)(out + (size_t)node * OUTF))[li * 2] = r;
    } else if (grp == 1) {
      f32x4 bv = ((const f32x4*)bias)[li * 2 + 1];
      f32x4 r;
      r.x = a4 * sc + bv.x; r.y = a5 * sc + bv.y;
      r.z = a6 * sc + bv.z; r.w = a7 * sc + bv.w;
      ((f32x4*)(out + (size_t)node * OUTF))[li * 2 + 1] = r;
    }
  }
}

extern "C" void kernel_launch(void* const* d_in, const int* in_sizes, int n_in,
                              void* d_out, int out_size, void* d_ws, size_t ws_size,
                              hipStream_t stream) {
  const float* feat   = (const float*)d_in[0];
  const float* weight = (const float*)d_in[1];
  const float* bias   = (const float*)d_in[2];
  const float* ew     = (const float*)d_in[3];
  const int*   src    = (const int*)d_in[4];
  const int*   dst    = (const int*)d_in[5];
  float* out = (float*)d_out;
  char* ws = (char*)d_ws;

  int* out_cnt        = (int*)ws;                          // 400 KB
  int* rowptr         = (int*)(ws + 0x80000);              // 400 KB + 4
  int* bucket_cnt     = (int*)(ws + 0x100000);             // 1.6 KB
  int* bucket_base    = (int*)(ws + 0x101000);             // 1.6 KB
  unsigned short* wta = (unsigned short*)(ws + 0x110000);  // 128 KB
  int2* bucket        = (int2*)(ws + 0x140000);            // 16.0 MB
  int2* epair         = (int2*)(ws + 0x1200000);           // 12.8 MB
  unsigned short* h   = (unsigned short*)(ws + 0x2000000); // 25.6 MB

  hipMemsetAsync(out_cnt, 0, NNODES * sizeof(int), stream);
  hipMemsetAsync(bucket_cnt, 0, NB * sizeof(int), stream);

  wt_kernel<<<32, 256, 0, stream>>>(weight, wta);
  bucket_kernel<<<(NEDGES + SEG - 1) / SEG, 256, 0, stream>>>(src, dst, ew, out_cnt,
                                                              bucket_cnt, bucket);
  bscan_kernel<<<1, 512, 0, stream>>>(bucket_cnt, bucket_base, rowptr);
  csr_kernel<<<NB, 256, 0, stream>>>(bucket_cnt, bucket_base, bucket, rowptr, epair);
  gemm_kernel<<<(NNODES + 127) / 128, 256, 0, stream>>>(feat, wta, out_cnt, h);
  gather_kernel<<<1024, 256, 0, stream>>>(rowptr, epair, h, bias, out);
}

// Round 8
// 251.714 us; speedup vs baseline: 5.4972x; 1.0731x over previous
//
#include <hip/hip_runtime.h>
#include <hip/hip_bf16.h>

#define NNODES 100000
#define NEDGES 1600000
#define INF 512
#define OUTF 128
#define NB 391          // buckets of 256 nodes: bucket = dst >> 8
#define BCAP 5120       // mean 4096, sigma ~64 -> 16 sigma headroom
#define SEG 2048        // edges per block in bucket_kernel (782 blocks, 3/CU)
#define BK 32           // gemm k-step (floats)
#define NKSTEP (INF / BK)

typedef __attribute__((ext_vector_type(8))) __bf16 bf16x8;
typedef __attribute__((ext_vector_type(4))) float f32x4;
typedef __attribute__((ext_vector_type(2))) float f32x2;

typedef const __attribute__((address_space(1))) unsigned int* gas_ptr;
typedef __attribute__((address_space(3))) unsigned int* las_ptr;

__device__ __forceinline__ void gload_lds16(const void* g, void* l) {
  __builtin_amdgcn_global_load_lds((gas_ptr)g, (las_ptr)l, 16, 0, 0);
}

// ---------------- weight f32 [512][128] -> bf16 fragment/lane-ordered -------
// short idx = kb*4096 + c8*512 + lane*8 + j  (lane = lg*16+l15)
//   value   = W[kb*32 + lg*8 + j][c8*16 + l15]
// -> B ds_read is lane-linear (conflict-free) AND staging is linear.
__global__ void wt_kernel(const float* __restrict__ w, unsigned short* __restrict__ wta) {
  int i = blockIdx.x * blockDim.x + threadIdx.x;   // 0..8191 int4s
  if (i >= 8192) return;
  int lane = i & 63;
  int c8   = (i >> 6) & 7;
  int kb   = i >> 9;
  int n = c8 * 16 + (lane & 15);
  int kbase = kb * 32 + (lane >> 4) * 8;
  unsigned short tmp[8];
#pragma unroll
  for (int j = 0; j < 8; ++j) {
    __bf16 b = (__bf16)(w[(size_t)(kbase + j) * OUTF + n]);
    tmp[j] = __builtin_bit_cast(unsigned short, b);
  }
  ((int4*)wta)[i] = *(int4*)tmp;
}

// ---------------- pass A: bucket edges by dst>>8, histogram src out-degree ---
__global__ __launch_bounds__(256) void bucket_kernel(
    const int* __restrict__ src, const int* __restrict__ dst,
    const float* __restrict__ ew, int* __restrict__ out_cnt,
    int* __restrict__ bucket_cnt, int2* __restrict__ bucket) {
  __shared__ int hist[NB];
  __shared__ int base[NB];
  int t = threadIdx.x;
  for (int i = t; i < NB; i += 256) hist[i] = 0;
  __syncthreads();
  int e0 = blockIdx.x * SEG;
  int e1 = min(e0 + SEG, NEDGES);
  for (int e = e0 + t; e < e1; e += 256) {
    atomicAdd(&out_cnt[src[e]], 1);
    atomicAdd(&hist[dst[e] >> 8], 1);
  }
  __syncthreads();
  for (int i = t; i < NB; i += 256) {
    int c = hist[i];
    base[i] = c ? atomicAdd(&bucket_cnt[i], c) : 0;
    hist[i] = 0;                       // reuse as cursor
  }
  __syncthreads();
  for (int e = e0 + t; e < e1; e += 256) {
    int d = dst[e];
    int b = d >> 8;
    int r = atomicAdd(&hist[b], 1);
    int2 en;
    en.x = ((d & 255) << 17) | src[e];  // src < 2^17
    en.y = __float_as_int(ew[e]);
    bucket[(size_t)b * BCAP + base[b] + r] = en;
  }
}

// ---------------- exclusive scan of bucket counts (1 block) -----------------
__global__ __launch_bounds__(512) void bscan_kernel(const int* __restrict__ bucket_cnt,
                                                    int* __restrict__ bucket_base,
                                                    int* __restrict__ rowptr) {
  __shared__ int s[512];
  int t = threadIdx.x;
  int v = (t < NB) ? bucket_cnt[t] : 0;
  s[t] = v;
  __syncthreads();
  for (int off = 1; off < 512; off <<= 1) {
    int x = (t >= off) ? s[t - off] : 0;
    __syncthreads();
    s[t] += x;
    __syncthreads();
  }
  if (t < NB) bucket_base[t] = s[t] - v;
  if (t == 0) rowptr[NNODES] = NEDGES;
}

// ---------------- pass B: bucket -> CSR (rowptr + epair) --------------------
__global__ __launch_bounds__(256) void csr_kernel(
    const int* __restrict__ bucket_cnt, const int* __restrict__ bucket_base,
    const int2* __restrict__ bucket, int* __restrict__ rowptr,
    int2* __restrict__ epair) {
  __shared__ int hist[256];
  __shared__ int cur[256];
  int b = blockIdx.x;
  int t = threadIdx.x;
  int nb = bucket_cnt[b];
  int bbase = bucket_base[b];
  const int2* bk = bucket + (size_t)b * BCAP;
  hist[t] = 0;
  __syncthreads();
  for (int i = t; i < nb; i += 256) atomicAdd(&hist[bk[i].x >> 17], 1);
  __syncthreads();
  int v = hist[t];
  for (int off = 1; off < 256; off <<= 1) {
    int x = (t >= off) ? hist[t - off] : 0;
    __syncthreads();
    hist[t] += x;
    __syncthreads();
  }
  int excl = hist[t] - v;
  int node = b * 256 + t;
  if (node < NNODES) rowptr[node] = bbase + excl;
  cur[t] = excl;
  __syncthreads();
  for (int i = t; i < nb; i += 256) {
    int2 en = bk[i];
    int nl = en.x >> 17;
    int r = atomicAdd(&cur[nl], 1);
    epair[bbase + r] = make_int2(en.x & 0x1FFFF, en.y);
  }
}

// ---------------- h = (feat * rsqrt(out_deg)) @ W, LDS-staged MFMA ----------
// 64-row x 128-col block tile, BK=32, 4 waves (each one 16-row fragment).
// LDS 32 KB total -> 5 blocks/CU, 20 waves/CU (TLP for HBM streaming).
// A: dbuf [64][32] f32, chunk-XOR-swizzled via pre-swizzled global source.
// B: dbuf 8 KB bf16 lane-ordered (wta layout) -> linear stage, lane-linear read.
__global__ __launch_bounds__(256, 4) void gemm_kernel(
    const float* __restrict__ feat, const unsigned short* __restrict__ wta,
    const int* __restrict__ out_cnt, unsigned short* __restrict__ h) {
  __shared__ float As[2][64 * BK];             // 8 KB each
  __shared__ unsigned short Bs[2][4096];       // 8 KB each

  const int t = threadIdx.x;
  const int lane = t & 63;
  const int wave = t >> 6;
  const int l15 = lane & 15;
  const int lg  = lane >> 4;
  const int rowbase = blockIdx.x * 64;

  const int srow_off = lane >> 3;              // 0..7
  const int schunk = (lane & 7) ^ srow_off;    // pre-swizzled source chunk

  int r0 = rowbase + wave * 16 + l15;
  float s0 = rsqrtf(fmaxf((float)out_cnt[min(r0, NNODES - 1)], 1.0f));

  f32x4 acc[8];
#pragma unroll
  for (int c = 0; c < 8; ++c) acc[c] = (f32x4){0.f, 0.f, 0.f, 0.f};

#define STAGE(buf, kb)                                                         \
  {                                                                            \
    _Pragma("unroll")                                                          \
    for (int q = 0; q < 2; ++q) {                                              \
      int i = wave * 2 + q;                                                    \
      int gr = min(rowbase + i * 8 + srow_off, NNODES - 1);                    \
      const float* ga = feat + (size_t)gr * INF + (kb) * BK + schunk * 4;      \
      gload_lds16(ga, &As[buf][i * 256]);                                      \
      const unsigned short* gb =                                               \
          wta + (size_t)(kb) * 4096 + i * 512 + lane * 8;                      \
      gload_lds16(gb, &Bs[buf][i * 512]);                                      \
    }                                                                          \
  }

  int buf = 0;
  STAGE(0, 0);
  __syncthreads();

  for (int kb = 0; kb < NKSTEP; ++kb) {
    if (kb + 1 < NKSTEP) STAGE(buf ^ 1, kb + 1);

    // B fragments: lane-linear b128, conflict-free
    bf16x8 bfr[8];
#pragma unroll
    for (int c = 0; c < 8; ++c)
      bfr[c] = *(const bf16x8*)&Bs[buf][c * 512 + lane * 8];

    // A fragment: row = wave*16+l15, logical chunks lg*2, lg*2+1 (XOR-swizzled)
    int r = wave * 16 + l15;
    int c0 = (lg * 2) ^ (l15 & 7);
    int c1 = (lg * 2 + 1) ^ (l15 & 7);
    f32x4 u = *(const f32x4*)&As[buf][r * 32 + c0 * 4];
    f32x4 v = *(const f32x4*)&As[buf][r * 32 + c1 * 4];
    bf16x8 a;
#pragma unroll
    for (int j = 0; j < 4; ++j) {
      a[j]     = (__bf16)(u[j] * s0);
      a[j + 4] = (__bf16)(v[j] * s0);
    }

#pragma unroll
    for (int c = 0; c < 8; ++c)
      acc[c] = __builtin_amdgcn_mfma_f32_16x16x32_bf16(a, bfr[c], acc[c], 0, 0, 0);

    __syncthreads();
    buf ^= 1;
  }
#undef STAGE

  int rb = rowbase + wave * 16 + lg * 4;
#pragma unroll
  for (int r = 0; r < 4; ++r) {
    int row = rb + r;
    if (row < NNODES) {
#pragma unroll
      for (int c = 0; c < 8; ++c) {
        __bf16 bv = (__bf16)acc[c][r];
        h[(size_t)row * OUTF + c * 16 + l15] = __builtin_bit_cast(unsigned short, bv);
      }
    }
  }
}

// ---------------- gather: 2 nodes per wave, register accumulation -----------
// lane bit5 -> which node of the pair; bit4 -> edge-interleave slot (stride 2);
// li = lane&15 covers feats li*8..li*8+7 (uint4 of bf16). One instruction
// stream drives TWO independent dependency chains. No atomics, no shfl
// broadcast. Cross-slot reduce: shfl_xor(16). Grid 2048 blocks -> 32 waves/CU.
__device__ __forceinline__ float blo(unsigned int u) { return __uint_as_float(u << 16); }
__device__ __forceinline__ float bhi(unsigned int u) { return __uint_as_float(u & 0xFFFF0000u); }

__global__ __launch_bounds__(256) void gather_kernel(
    const int* __restrict__ rowptr, const int2* __restrict__ epair,
    const unsigned short* __restrict__ h, const float* __restrict__ bias,
    float* __restrict__ out) {
  const int lane = threadIdx.x & 63;
  const int half = lane >> 5;          // node select within pair
  const int grp  = (lane >> 4) & 1;    // edge interleave slot
  const int li   = lane & 15;          // feature slice
  const int wid  = (blockIdx.x * blockDim.x + threadIdx.x) >> 6;
  const int nw   = (gridDim.x * blockDim.x) >> 6;

  for (int p = wid; p < NNODES / 2; p += nw) {
    const int node = p * 2 + half;     // NNODES even
    const int beg = rowptr[node];
    const int end = rowptr[node + 1];

    float a0 = 0.f, a1 = 0.f, a2 = 0.f, a3 = 0.f;
    float a4 = 0.f, a5 = 0.f, a6 = 0.f, a7 = 0.f;

    int e = beg + grp;
#define GSTEP(pr)                                                              \
      {                                                                        \
        const unsigned int* hp =                                               \
            (const unsigned int*)(h + (size_t)(pr).x * OUTF) + li * 4;         \
        uint4 u = *(const uint4*)hp;                                           \
        float w = __int_as_float((pr).y);                                      \
        a0 += blo(u.x) * w; a1 += bhi(u.x) * w;                                \
        a2 += blo(u.y) * w; a3 += bhi(u.y) * w;                                \
        a4 += blo(u.z) * w; a5 += bhi(u.z) * w;                                \
        a6 += blo(u.w) * w; a7 += bhi(u.w) * w;                                \
      }
    for (; e + 6 < end; e += 8) {
      int2 p0 = epair[e];
      int2 p1 = epair[e + 2];
      int2 p2 = epair[e + 4];
      int2 p3 = epair[e + 6];
      GSTEP(p0); GSTEP(p1); GSTEP(p2); GSTEP(p3);
    }
    for (; e < end; e += 2) {
      int2 pr = epair[e];
      GSTEP(pr);
    }
#undef GSTEP

    // combine the two interleave slots (lanes differing in bit 4)
    a0 += __shfl_xor(a0, 16); a1 += __shfl_xor(a1, 16);
    a2 += __shfl_xor(a2, 16); a3 += __shfl_xor(a3, 16);
    a4 += __shfl_xor(a4, 16); a5 += __shfl_xor(a5, 16);
    a6 += __shfl_xor(a6, 16); a7 += __shfl_xor(a7, 16);

    if (grp == 0) {
      float sc = rsqrtf(fmaxf((float)(end - beg), 1.0f));
      f32x4 b0 = ((const f32x4*)bias)[li * 2];
      f32x4 b1 = ((const f32x4*)bias)[li * 2 + 1];
      f32x4 v0, v1;
      v0.x = a0 * sc + b0.x; v0.y = a1 * sc + b0.y;
      v0.z = a2 * sc + b0.z; v0.w = a3 * sc + b0.w;
      v1.x = a4 * sc + b1.x; v1.y = a5 * sc + b1.y;
      v1.z = a6 * sc + b1.z; v1.w = a7 * sc + b1.w;
      f32x4* op = (f32x4*)(out + (size_t)node * OUTF);
      op[li * 2] = v0;
      op[li * 2 + 1] = v1;
    }
  }
}

extern "C" void kernel_launch(void* const* d_in, const int* in_sizes, int n_in,
                              void* d_out, int out_size, void* d_ws, size_t ws_size,
                              hipStream_t stream) {
  const float* feat   = (const float*)d_in[0];
  const float* weight = (const float*)d_in[1];
  const float* bias   = (const float*)d_in[2];
  const float* ew     = (const float*)d_in[3];
  const int*   src    = (const int*)d_in[4];
  const int*   dst    = (const int*)d_in[5];
  float* out = (float*)d_out;
  char* ws = (char*)d_ws;

  int* out_cnt        = (int*)ws;                          // 400 KB
  int* rowptr         = (int*)(ws + 0x80000);              // 400 KB + 4
  int* bucket_cnt     = (int*)(ws + 0x100000);             // 1.6 KB
  int* bucket_base    = (int*)(ws + 0x101000);             // 1.6 KB
  unsigned short* wta = (unsigned short*)(ws + 0x110000);  // 128 KB
  int2* bucket        = (int2*)(ws + 0x140000);            // 16.0 MB
  int2* epair         = (int2*)(ws + 0x1200000);           // 12.8 MB
  unsigned short* h   = (unsigned short*)(ws + 0x2000000); // 25.6 MB

  hipMemsetAsync(out_cnt, 0, NNODES * sizeof(int), stream);
  hipMemsetAsync(bucket_cnt, 0, NB * sizeof(int), stream);

  wt_kernel<<<32, 256, 0, stream>>>(weight, wta);
  bucket_kernel<<<(NEDGES + SEG - 1) / SEG, 256, 0, stream>>>(src, dst, ew, out_cnt,
                                                              bucket_cnt, bucket);
  bscan_kernel<<<1, 512, 0, stream>>>(bucket_cnt, bucket_base, rowptr);
  csr_kernel<<<NB, 256, 0, stream>>>(bucket_cnt, bucket_base, bucket, rowptr, epair);
  gemm_kernel<<<(NNODES + 63) / 64, 256, 0, stream>>>(feat, wta, out_cnt, h);
  gather_kernel<<<2048, 256, 0, stream>>>(rowptr, epair, h, bias, out);
}